// Round 22
// baseline (483.246 us; speedup 1.0000x reference)
//
#include <hip/hip_runtime.h>
#include <hip/hip_bf16.h>
#include <math.h>

// EarthAttention3D constants
#define B_   96
#define NW   10
#define NN   144
#define CC   192
#define HH   6
#define DH   32
#define SCALE 0.17677669529663687f  // 1/sqrt(32)

#define XP 200   // xs pitch (bf16): 400 B rows
#define PP 152   // Ps pitch: 304 B rows (12-bank row stride -> <=2-way, free)
#define NBW (B_ * NW)        // 960 (b,w) pairs total
#define QKV_STRIDE (NN * DH) // 4608 elems per (h,s) matrix
#define MAXCHUNK_L3 240      // cap bw-chunk so the qkv chunk (40 MB) stays L3-hot

typedef __attribute__((ext_vector_type(8))) short v8s;            // 8 x bf16
typedef __attribute__((ext_vector_type(4))) unsigned short v4us;  // 4 x bf16
typedef __attribute__((ext_vector_type(4))) float v4f;            // MFMA acc

// fp32 -> bf16 RNE via the compiler's native lowering.
__device__ __forceinline__ unsigned short f2b(float f) {
  __hip_bfloat16 h = __float2bfloat16(f);
  return *reinterpret_cast<unsigned short*>(&h);
}
__device__ __forceinline__ float b2f(unsigned short s) {
  union { unsigned u; float f; } v; v.u = ((unsigned)s) << 16;
  return v.f;
}

#define N_WQT (576*192)
#define N_WPT (192*192)
#define N_BIAS (NW*HH*NN*NN)

// ---------------------------------------------------------------------------
// Prep: wqT = w_qkv^T bf16, wpT = w_proj^T bf16, biasNN gathered bf16.
// ---------------------------------------------------------------------------
__global__ __launch_bounds__(256) void prep_kernel(
    const float* __restrict__ w_qkv, const float* __restrict__ w_proj,
    const float* __restrict__ bias_table, const int* __restrict__ pos,
    unsigned short* __restrict__ wqT, unsigned short* __restrict__ wpT,
    unsigned short* __restrict__ biasNN)
{
  int i = blockIdx.x * 256 + threadIdx.x;
  if (i < N_WQT) {
    int n = i / 192, k = i % 192;
    wqT[i] = f2b(w_qkv[k * 576 + n]);
  } else if (i < N_WQT + N_WPT) {
    int j = i - N_WQT;
    int n = j / 192, k = j % 192;
    wpT[j] = f2b(w_proj[k * 192 + n]);
  } else if (i < N_WQT + N_WPT + N_BIAS) {
    int j = i - (N_WQT + N_WPT);
    int m = j % NN, n = (j / NN) % NN, h = (j / (NN * NN)) % HH, w = j / (NN * NN * HH);
    biasNN[j] = f2b(bias_table[(pos[n * NN + m] * NW + w) * HH + h]);
  }
}

// ---------------------------------------------------------------------------
// QKV GEMM v3: ONE block per bw, 256 thr / 4 waves, 57.6 KB LDS
// -> 2 blocks/CU. x staged ONCE (packed v4us stores), each wqT strip load
// feeds 54 MFMAs. wqT strip loads double-buffered in registers.
// ---------------------------------------------------------------------------
__global__ __launch_bounds__(256, 2) void qkv_gemm(
    const float* __restrict__ x, const float* __restrict__ b_qkv,
    const unsigned short* __restrict__ wqT,
    unsigned short* __restrict__ qkv, int bw0)
{
  __shared__ unsigned short xs[NN * XP];   // 57,600 B
  const int tid  = threadIdx.x;
  const int wave = tid >> 6, lane = tid & 63;
  const int lr = lane & 15, lk8 = (lane >> 4) * 8, quad = lane >> 4;
  const int bwl = blockIdx.x;
  const int bw  = bw0 + bwl;

  // stage all 144 rows of x as bf16 (packed 8B LDS stores)
  const float4* xp4 = (const float4*)(x + (size_t)bw * NN * CC);
  for (int i = tid; i < NN * (CC / 4); i += 256) {
    float4 f = xp4[i];
    int r = i / (CC / 4), c = (i % (CC / 4)) * 4;
    v4us pk;
    pk[0] = f2b(f.x); pk[1] = f2b(f.y); pk[2] = f2b(f.z); pk[3] = f2b(f.w);
    *(v4us*)&xs[r * XP + c] = pk;
  }
  __syncthreads();

  // software pipeline over the 9 col-strips this wave owns: c = wave + 4*i
  v8s bf0[6], bf1[6];
  {
    const unsigned short* w0 = wqT + (size_t)(wave * 16 + lr) * CC;
    #pragma unroll
    for (int ks = 0; ks < 6; ks++) bf0[ks] = *(const v8s*)&w0[ks * 32 + lk8];
  }

  #pragma unroll
  for (int i = 0; i < 9; i++) {
    const int c = wave + i * 4;
    // prefetch strip i+1 into the other buffer
    if (i + 1 < 9) {
      const unsigned short* wn = wqT + (size_t)((c + 4) * 16 + lr) * CC;
      if (i & 1) {
        #pragma unroll
        for (int ks = 0; ks < 6; ks++) bf0[ks] = *(const v8s*)&wn[ks * 32 + lk8];
      } else {
        #pragma unroll
        for (int ks = 0; ks < 6; ks++) bf1[ks] = *(const v8s*)&wn[ks * 32 + lk8];
      }
    }

    const int s = c / 12;
    const int h = (c % 12) >> 1;
    const int dhalf = c & 1;
    const float bv = b_qkv[c * 16 + lr];
    v4f acc[9];
    #pragma unroll
    for (int ii = 0; ii < 9; ii++) acc[ii] = (v4f){bv, bv, bv, bv};

    // 9 row-tiles x 6 ks: per ks read 9 independent A-frags, 9 indep MFMAs
    #pragma unroll
    for (int ks = 0; ks < 6; ks++) {
      v8s at[9];
      #pragma unroll
      for (int ii = 0; ii < 9; ii++)
        at[ii] = *(const v8s*)&xs[(ii * 16 + lr) * XP + ks * 32 + lk8];
      if (i & 1) {
        #pragma unroll
        for (int ii = 0; ii < 9; ii++)
          acc[ii] = __builtin_amdgcn_mfma_f32_16x16x32_bf16(at[ii], bf1[ks], acc[ii], 0, 0, 0);
      } else {
        #pragma unroll
        for (int ii = 0; ii < 9; ii++)
          acc[ii] = __builtin_amdgcn_mfma_f32_16x16x32_bf16(at[ii], bf0[ks], acc[ii], 0, 0, 0);
      }
    }

    if (s == 2) {
      // V: store transposed [d][n], 4 n packed per 8B store
      unsigned short* opT = qkv + ((size_t)(bwl * HH + h) * 3 + 2) * QKV_STRIDE
                          + (size_t)(dhalf * 16 + lr) * NN;
      #pragma unroll
      for (int ii = 0; ii < 9; ii++) {
        const int n0 = ii * 16 + quad * 4;
        v4us pk;
        #pragma unroll
        for (int r = 0; r < 4; r++) pk[r] = f2b(acc[ii][r]);
        *(v4us*)&opT[n0] = pk;
      }
    } else {
      unsigned short* op = qkv + ((size_t)(bwl * HH + h) * 3 + s) * QKV_STRIDE + dhalf * 16 + lr;
      #pragma unroll
      for (int ii = 0; ii < 9; ii++)
        #pragma unroll
        for (int r = 0; r < 4; r++) {
          const int n = ii * 16 + quad * 4 + r;
          op[n * DH] = f2b(acc[ii][r]);
        }
    }
  }
}

// ---------------------------------------------------------------------------
// Attention per (b,w,h) — R20 measured-best version: 256 thr / 4 waves,
// 43.8 KB LDS, (256,3). Phase B pure MFMA->LDS; bias+mask folded into the
// coalesced softmax read.
// ---------------------------------------------------------------------------
__global__ __launch_bounds__(256, 3) void attn_bwh(
    const unsigned short* __restrict__ qkv, const float* __restrict__ mask,
    const unsigned short* __restrict__ biasNN,
    unsigned short* __restrict__ ao, int bw0)
{
  __shared__ unsigned short Ps[NN * PP];   // 43,776 B

  const int tid  = threadIdx.x;
  const int wave = tid >> 6, lane = tid & 63;
  const int lr = lane & 15, lk8 = (lane >> 4) * 8, quad = lane >> 4;

  const int bwl = blockIdx.x / HH;
  const int h   = blockIdx.x % HH;
  const int bw  = bw0 + bwl;
  const int b   = bw / NW;
  const int w   = bw % NW;

  const unsigned short* qp = qkv + (size_t)(bwl * HH + h) * 3 * QKV_STRIDE;
  const unsigned short* kp = qp + QKV_STRIDE;
  const unsigned short* vT = qp + 2 * QKV_STRIDE;   // [32][144] transposed

  // hoist phase-D V^T fragments NOW: loads complete under the barrier drain
  v8s bv[2][4], bvt[2];
  #pragma unroll
  for (int dh2 = 0; dh2 < 2; dh2++) {
    const unsigned short* vrow = vT + (size_t)(dh2 * 16 + lr) * NN;
    #pragma unroll
    for (int ks = 0; ks < 4; ks++) bv[dh2][ks] = *(const v8s*)&vrow[ks * 32 + lk8];
    bvt[dh2] = *(const v8s*)&vrow[128 + (lk8 & 8)];
  }

  // ---- phase B: S = scale * q k^T -> bf16 in Ps (no global gathers) -------
  v8s aq[9];
  #pragma unroll
  for (int nt = 0; nt < 9; nt++)
    aq[nt] = *(const v8s*)&qp[(nt * 16 + lr) * DH + lk8];

  for (int mt = wave; mt < 9; mt += 4) {
    v8s bk = *(const v8s*)&kp[(mt * 16 + lr) * DH + lk8];
    const int m = mt * 16 + lr;
    #pragma unroll
    for (int nt = 0; nt < 9; nt++) {
      v4f c = {0.f, 0.f, 0.f, 0.f};
      c = __builtin_amdgcn_mfma_f32_16x16x32_bf16(aq[nt], bk, c, 0, 0, 0);
      #pragma unroll
      for (int r = 0; r < 4; r++) {
        const int n = nt * 16 + quad * 4 + r;
        Ps[n * PP + m] = f2b(c[r] * SCALE);
      }
    }
  }
  __syncthreads();

  // ---- softmax + bias + mask: one 16-lane group per row -------------------
  const unsigned short* bp = biasNN + (size_t)(w * HH + h) * NN * NN;
  const float* mp = mask + (size_t)b * NN * NN;
  for (int rr = 0; rr < 9; rr++) {
    const int row = rr * 16 + wave * 4 + quad;
    unsigned short* prow = &Ps[row * PP];
    const unsigned short* brow = bp + (size_t)row * NN;
    const float* mrow = mp + (size_t)row * NN;
    float bm[9];
    #pragma unroll
    for (int j = 0; j < 9; j++)
      bm[j] = b2f(brow[j * 16 + lr]) + mrow[j * 16 + lr];
    float e[9];
    float mx = -1e30f;
    #pragma unroll
    for (int j = 0; j < 9; j++) {
      e[j] = b2f(prow[j * 16 + lr]) + bm[j];
      mx = fmaxf(mx, e[j]);
    }
    #pragma unroll
    for (int off = 8; off; off >>= 1) mx = fmaxf(mx, __shfl_xor(mx, off, 64));
    float s = 0.f;
    #pragma unroll
    for (int j = 0; j < 9; j++) { e[j] = __expf(e[j] - mx); s += e[j]; }
    #pragma unroll
    for (int off = 8; off; off >>= 1) s += __shfl_xor(s, off, 64);
    const float inv = 1.f / s;
    #pragma unroll
    for (int j = 0; j < 9; j++) prow[j * 16 + lr] = f2b(e[j] * inv);
  }
  __syncthreads();

  // ---- phase D: O = P @ v; V^T fragments already in registers -------------
  const v8s vzero = {};
  for (int nt = wave; nt < 9; nt += 4) {
    v8s ap[4];
    #pragma unroll
    for (int ks = 0; ks < 4; ks++)
      ap[ks] = *(const v8s*)&Ps[(nt * 16 + lr) * PP + ks * 32 + lk8];
    v8s at = *(const v8s*)&Ps[(nt * 16 + lr) * PP + 128 + (lk8 & 8)];
    at = (quad < 2) ? at : vzero;   // k = 144..159 contributes zero
    #pragma unroll
    for (int dh2 = 0; dh2 < 2; dh2++) {
      v4f c = {0.f, 0.f, 0.f, 0.f};
      #pragma unroll
      for (int ks = 0; ks < 4; ks++)
        c = __builtin_amdgcn_mfma_f32_16x16x32_bf16(ap[ks], bv[dh2][ks], c, 0, 0, 0);
      c = __builtin_amdgcn_mfma_f32_16x16x32_bf16(at, bvt[dh2], c, 0, 0, 0);
      #pragma unroll
      for (int r = 0; r < 4; r++) {
        const int n = nt * 16 + quad * 4 + r;
        ao[((size_t)bw * NN + n) * CC + h * DH + dh2 * 16 + lr] = f2b(c[r]);
      }
    }
  }
}

// ---------------------------------------------------------------------------
// Proj v2: out = ao(bf16) @ w_proj + b_proj. 64 rows/block, NO LDS, NO
// barriers. Wave w owns output cols j in {3w..3w+2}; its 18 wpT fragments
// live in registers for the whole block. A-fragments read direct from
// global (LLC/L1-hot).
// ---------------------------------------------------------------------------
__global__ __launch_bounds__(256) void proj_mfma(
    const unsigned short* __restrict__ ao,
    const unsigned short* __restrict__ wpT,
    const float* __restrict__ b_proj,
    float* __restrict__ out)
{
  const int tid  = threadIdx.x;
  const int wave = tid >> 6, lane = tid & 63;
  const int lr = lane & 15, lk8 = (lane >> 4) * 8, quad = lane >> 4;
  const size_t row0 = (size_t)blockIdx.x * 64;
  const int j0 = wave * 3;   // 3 j-strips of 16 cols per wave = 48 cols

  v8s bf[3][6];
  #pragma unroll
  for (int jj = 0; jj < 3; jj++)
    #pragma unroll
    for (int ks = 0; ks < 6; ks++)
      bf[jj][ks] = *(const v8s*)(wpT + (size_t)((j0 + jj) * 16 + lr) * CC + ks * 32 + lk8);

  float bvj[3];
  #pragma unroll
  for (int jj = 0; jj < 3; jj++) bvj[jj] = b_proj[(j0 + jj) * 16 + lr];

  #pragma unroll
  for (int rt = 0; rt < 4; rt++) {
    const size_t r0 = row0 + rt * 16;
    v8s a[6];
    #pragma unroll
    for (int ks = 0; ks < 6; ks++)
      a[ks] = *(const v8s*)(ao + (r0 + lr) * CC + ks * 32 + lk8);
    v4f acc[3];
    #pragma unroll
    for (int jj = 0; jj < 3; jj++) acc[jj] = (v4f){bvj[jj], bvj[jj], bvj[jj], bvj[jj]};
    #pragma unroll
    for (int ks = 0; ks < 6; ks++)
      #pragma unroll
      for (int jj = 0; jj < 3; jj++)
        acc[jj] = __builtin_amdgcn_mfma_f32_16x16x32_bf16(a[ks], bf[jj][ks], acc[jj], 0, 0, 0);
    #pragma unroll
    for (int jj = 0; jj < 3; jj++)
      #pragma unroll
      for (int r = 0; r < 4; r++)
        out[(r0 + quad * 4 + r) * CC + (j0 + jj) * 16 + lr] = acc[jj][r];
  }
}

// ---------------------------------------------------------------------------
// Launcher: chunked so the per-pass qkv tensor (<=40 MB at 240 bw) stays
// L3-resident between qkv_gemm (producer) and attn_bwh (consumer).
// ---------------------------------------------------------------------------
extern "C" void kernel_launch(void* const* d_in, const int* in_sizes, int n_in,
                              void* d_out, int out_size, void* d_ws, size_t ws_size,
                              hipStream_t stream)
{
  const float* x          = (const float*)d_in[0];
  const float* mask       = (const float*)d_in[1];
  const float* w_qkv      = (const float*)d_in[2];
  const float* b_qkv      = (const float*)d_in[3];
  const float* w_proj     = (const float*)d_in[4];
  const float* b_proj     = (const float*)d_in[5];
  const float* bias_table = (const float*)d_in[6];
  const int*   pos        = (const int*)d_in[7];
  float* out = (float*)d_out;

  // ws layout (bf16 elems): biasNN | wqT | wpT | ao | qkvws (variable)
  unsigned short* biasNN = (unsigned short*)d_ws;                   // 1,244,160
  unsigned short* wqT    = biasNN + N_BIAS;                         //   110,592
  unsigned short* wpT    = wqT + N_WQT;                             //    36,864
  unsigned short* ao     = wpT + N_WPT;                             // 26,542,080
  unsigned short* qkvws  = ao + (size_t)B_ * NW * NN * CC;

  // runtime chunk sizing, capped at MAXCHUNK_L3 for L3 residency
  const size_t fixed_bytes = (size_t)(qkvws - (unsigned short*)d_ws) * sizeof(unsigned short);
  const size_t per_bw      = (size_t)HH * 3 * QKV_STRIDE * sizeof(unsigned short); // 165,888 B
  size_t avail = (ws_size > fixed_bytes) ? (ws_size - fixed_bytes) : 0;
  int maxchunk = (int)(avail / per_bw);
  if (maxchunk < 60)  maxchunk = 60;    // degenerate floor
  if (maxchunk > MAXCHUNK_L3) maxchunk = MAXCHUNK_L3;
  const int npass = (NBW + maxchunk - 1) / maxchunk;
  const int chunk = (NBW + npass - 1) / npass;

  const int prep_total = N_WQT + N_WPT + N_BIAS;
  prep_kernel<<<(prep_total + 255) / 256, 256, 0, stream>>>(
      w_qkv, w_proj, bias_table, pos, wqT, wpT, biasNN);

  for (int bw0 = 0; bw0 < NBW; bw0 += chunk) {
    const int cur = (NBW - bw0 < chunk) ? (NBW - bw0) : chunk;
    qkv_gemm<<<cur, 256, 0, stream>>>(x, b_qkv, wqT, qkvws, bw0);
    attn_bwh<<<cur * HH, 256, 0, stream>>>(qkvws, mask, biasNN, ao, bw0);
  }
  proj_mfma<<<(B_ * NW * NN) / 64, 256, 0, stream>>>(ao, wpT, b_proj, out);
}

// Round 24
// 425.843 us; speedup vs baseline: 1.1348x; 1.1348x over previous
//
#include <hip/hip_runtime.h>
#include <hip/hip_bf16.h>
#include <math.h>

// EarthAttention3D constants
#define B_   96
#define NW   10
#define NN   144
#define CC   192
#define HH   6
#define DH   32
#define SCALE 0.17677669529663687f  // 1/sqrt(32)

#define XP 200   // xs pitch (bf16): 400 B rows
#define PP 152   // Ps pitch: 304 B rows (12-bank row stride -> <=2-way, free)
#define NBW (B_ * NW)        // 960 (b,w) pairs total
#define QKV_STRIDE (NN * DH) // 4608 elems per (h,s) matrix

typedef __attribute__((ext_vector_type(8))) short v8s;            // 8 x bf16
typedef __attribute__((ext_vector_type(4))) unsigned short v4us;  // 4 x bf16
typedef __attribute__((ext_vector_type(4))) float v4f;            // MFMA acc

// fp32 -> bf16 RNE via the compiler's native lowering.
__device__ __forceinline__ unsigned short f2b(float f) {
  __hip_bfloat16 h = __float2bfloat16(f);
  return *reinterpret_cast<unsigned short*>(&h);
}
__device__ __forceinline__ float b2f(unsigned short s) {
  union { unsigned u; float f; } v; v.u = ((unsigned)s) << 16;
  return v.f;
}

#define N_WQT (576*192)
#define N_WPT (192*192)
#define N_BIAS (NW*HH*NN*NN)

// ---------------------------------------------------------------------------
// Prep: wqT = w_qkv^T bf16, wpT = w_proj^T bf16, biasNN gathered bf16.
// ---------------------------------------------------------------------------
__global__ __launch_bounds__(256) void prep_kernel(
    const float* __restrict__ w_qkv, const float* __restrict__ w_proj,
    const float* __restrict__ bias_table, const int* __restrict__ pos,
    unsigned short* __restrict__ wqT, unsigned short* __restrict__ wpT,
    unsigned short* __restrict__ biasNN)
{
  int i = blockIdx.x * 256 + threadIdx.x;
  if (i < N_WQT) {
    int n = i / 192, k = i % 192;
    wqT[i] = f2b(w_qkv[k * 576 + n]);
  } else if (i < N_WQT + N_WPT) {
    int j = i - N_WQT;
    int n = j / 192, k = j % 192;
    wpT[j] = f2b(w_proj[k * 192 + n]);
  } else if (i < N_WQT + N_WPT + N_BIAS) {
    int j = i - (N_WQT + N_WPT);
    int m = j % NN, n = (j / NN) % NN, h = (j / (NN * NN)) % HH, w = j / (NN * NN * HH);
    biasNN[j] = f2b(bias_table[(pos[n * NN + m] * NW + w) * HH + h]);
  }
}

// ---------------------------------------------------------------------------
// QKV GEMM v3: ONE block per bw (960 blocks), 256 thr / 4 waves, 57.6 KB LDS
// -> 2 blocks/CU. x staged ONCE (packed v4us stores), each wqT strip load
// feeds 54 MFMAs. wqT strip loads double-buffered in registers.
// ---------------------------------------------------------------------------
__global__ __launch_bounds__(256, 2) void qkv_gemm(
    const float* __restrict__ x, const float* __restrict__ b_qkv,
    const unsigned short* __restrict__ wqT,
    unsigned short* __restrict__ qkv, int bw0)
{
  __shared__ unsigned short xs[NN * XP];   // 57,600 B
  const int tid  = threadIdx.x;
  const int wave = tid >> 6, lane = tid & 63;
  const int lr = lane & 15, lk8 = (lane >> 4) * 8, quad = lane >> 4;
  const int bwl = blockIdx.x;
  const int bw  = bw0 + bwl;

  // stage all 144 rows of x as bf16 (packed 8B LDS stores)
  const float4* xp4 = (const float4*)(x + (size_t)bw * NN * CC);
  for (int i = tid; i < NN * (CC / 4); i += 256) {
    float4 f = xp4[i];
    int r = i / (CC / 4), c = (i % (CC / 4)) * 4;
    v4us pk;
    pk[0] = f2b(f.x); pk[1] = f2b(f.y); pk[2] = f2b(f.z); pk[3] = f2b(f.w);
    *(v4us*)&xs[r * XP + c] = pk;
  }
  __syncthreads();

  // software pipeline over the 9 col-strips this wave owns: c = wave + 4*i
  v8s bf0[6], bf1[6];
  {
    const unsigned short* w0 = wqT + (size_t)(wave * 16 + lr) * CC;
    #pragma unroll
    for (int ks = 0; ks < 6; ks++) bf0[ks] = *(const v8s*)&w0[ks * 32 + lk8];
  }

  #pragma unroll
  for (int i = 0; i < 9; i++) {
    const int c = wave + i * 4;
    // prefetch strip i+1 into the other buffer
    if (i + 1 < 9) {
      const unsigned short* wn = wqT + (size_t)((c + 4) * 16 + lr) * CC;
      if (i & 1) {
        #pragma unroll
        for (int ks = 0; ks < 6; ks++) bf0[ks] = *(const v8s*)&wn[ks * 32 + lk8];
      } else {
        #pragma unroll
        for (int ks = 0; ks < 6; ks++) bf1[ks] = *(const v8s*)&wn[ks * 32 + lk8];
      }
    }

    const int s = c / 12;
    const int h = (c % 12) >> 1;
    const int dhalf = c & 1;
    const float bv = b_qkv[c * 16 + lr];
    v4f acc[9];
    #pragma unroll
    for (int ii = 0; ii < 9; ii++) acc[ii] = (v4f){bv, bv, bv, bv};

    // 9 row-tiles x 6 ks: per ks read 9 independent A-frags, 9 indep MFMAs
    #pragma unroll
    for (int ks = 0; ks < 6; ks++) {
      v8s at[9];
      #pragma unroll
      for (int ii = 0; ii < 9; ii++)
        at[ii] = *(const v8s*)&xs[(ii * 16 + lr) * XP + ks * 32 + lk8];
      if (i & 1) {
        #pragma unroll
        for (int ii = 0; ii < 9; ii++)
          acc[ii] = __builtin_amdgcn_mfma_f32_16x16x32_bf16(at[ii], bf1[ks], acc[ii], 0, 0, 0);
      } else {
        #pragma unroll
        for (int ii = 0; ii < 9; ii++)
          acc[ii] = __builtin_amdgcn_mfma_f32_16x16x32_bf16(at[ii], bf0[ks], acc[ii], 0, 0, 0);
      }
    }

    if (s == 2) {
      // V: store transposed [d][n], 4 n packed per 8B store
      unsigned short* opT = qkv + ((size_t)(bwl * HH + h) * 3 + 2) * QKV_STRIDE
                          + (size_t)(dhalf * 16 + lr) * NN;
      #pragma unroll
      for (int ii = 0; ii < 9; ii++) {
        const int n0 = ii * 16 + quad * 4;
        v4us pk;
        #pragma unroll
        for (int r = 0; r < 4; r++) pk[r] = f2b(acc[ii][r]);
        *(v4us*)&opT[n0] = pk;
      }
    } else {
      unsigned short* op = qkv + ((size_t)(bwl * HH + h) * 3 + s) * QKV_STRIDE + dhalf * 16 + lr;
      #pragma unroll
      for (int ii = 0; ii < 9; ii++)
        #pragma unroll
        for (int r = 0; r < 4; r++) {
          const int n = ii * 16 + quad * 4 + r;
          op[n * DH] = f2b(acc[ii][r]);
        }
    }
  }
}

// ---------------------------------------------------------------------------
// Attention per (b,w,h) — R20 measured-best version: 256 thr / 4 waves,
// 43.8 KB LDS, (256,3). Phase B pure MFMA->LDS; bias+mask folded into the
// coalesced softmax read.
// ---------------------------------------------------------------------------
__global__ __launch_bounds__(256, 3) void attn_bwh(
    const unsigned short* __restrict__ qkv, const float* __restrict__ mask,
    const unsigned short* __restrict__ biasNN,
    unsigned short* __restrict__ ao, int bw0)
{
  __shared__ unsigned short Ps[NN * PP];   // 43,776 B

  const int tid  = threadIdx.x;
  const int wave = tid >> 6, lane = tid & 63;
  const int lr = lane & 15, lk8 = (lane >> 4) * 8, quad = lane >> 4;

  const int bwl = blockIdx.x / HH;
  const int h   = blockIdx.x % HH;
  const int bw  = bw0 + bwl;
  const int b   = bw / NW;
  const int w   = bw % NW;

  const unsigned short* qp = qkv + (size_t)(bwl * HH + h) * 3 * QKV_STRIDE;
  const unsigned short* kp = qp + QKV_STRIDE;
  const unsigned short* vT = qp + 2 * QKV_STRIDE;   // [32][144] transposed

  // hoist phase-D V^T fragments NOW: loads complete under the barrier drain
  v8s bv[2][4], bvt[2];
  #pragma unroll
  for (int dh2 = 0; dh2 < 2; dh2++) {
    const unsigned short* vrow = vT + (size_t)(dh2 * 16 + lr) * NN;
    #pragma unroll
    for (int ks = 0; ks < 4; ks++) bv[dh2][ks] = *(const v8s*)&vrow[ks * 32 + lk8];
    bvt[dh2] = *(const v8s*)&vrow[128 + (lk8 & 8)];
  }

  // ---- phase B: S = scale * q k^T -> bf16 in Ps (no global gathers) -------
  v8s aq[9];
  #pragma unroll
  for (int nt = 0; nt < 9; nt++)
    aq[nt] = *(const v8s*)&qp[(nt * 16 + lr) * DH + lk8];

  for (int mt = wave; mt < 9; mt += 4) {
    v8s bk = *(const v8s*)&kp[(mt * 16 + lr) * DH + lk8];
    const int m = mt * 16 + lr;
    #pragma unroll
    for (int nt = 0; nt < 9; nt++) {
      v4f c = {0.f, 0.f, 0.f, 0.f};
      c = __builtin_amdgcn_mfma_f32_16x16x32_bf16(aq[nt], bk, c, 0, 0, 0);
      #pragma unroll
      for (int r = 0; r < 4; r++) {
        const int n = nt * 16 + quad * 4 + r;
        Ps[n * PP + m] = f2b(c[r] * SCALE);
      }
    }
  }
  __syncthreads();

  // ---- softmax + bias + mask: one 16-lane group per row -------------------
  const unsigned short* bp = biasNN + (size_t)(w * HH + h) * NN * NN;
  const float* mp = mask + (size_t)b * NN * NN;
  for (int rr = 0; rr < 9; rr++) {
    const int row = rr * 16 + wave * 4 + quad;
    unsigned short* prow = &Ps[row * PP];
    const unsigned short* brow = bp + (size_t)row * NN;
    const float* mrow = mp + (size_t)row * NN;
    float bm[9];
    #pragma unroll
    for (int j = 0; j < 9; j++)
      bm[j] = b2f(brow[j * 16 + lr]) + mrow[j * 16 + lr];
    float e[9];
    float mx = -1e30f;
    #pragma unroll
    for (int j = 0; j < 9; j++) {
      e[j] = b2f(prow[j * 16 + lr]) + bm[j];
      mx = fmaxf(mx, e[j]);
    }
    #pragma unroll
    for (int off = 8; off; off >>= 1) mx = fmaxf(mx, __shfl_xor(mx, off, 64));
    float s = 0.f;
    #pragma unroll
    for (int j = 0; j < 9; j++) { e[j] = __expf(e[j] - mx); s += e[j]; }
    #pragma unroll
    for (int off = 8; off; off >>= 1) s += __shfl_xor(s, off, 64);
    const float inv = 1.f / s;
    #pragma unroll
    for (int j = 0; j < 9; j++) prow[j * 16 + lr] = f2b(e[j] * inv);
  }
  __syncthreads();

  // ---- phase D: O = P @ v; V^T fragments already in registers -------------
  const v8s vzero = {};
  for (int nt = wave; nt < 9; nt += 4) {
    v8s ap[4];
    #pragma unroll
    for (int ks = 0; ks < 4; ks++)
      ap[ks] = *(const v8s*)&Ps[(nt * 16 + lr) * PP + ks * 32 + lk8];
    v8s at = *(const v8s*)&Ps[(nt * 16 + lr) * PP + 128 + (lk8 & 8)];
    at = (quad < 2) ? at : vzero;   // k = 144..159 contributes zero
    #pragma unroll
    for (int dh2 = 0; dh2 < 2; dh2++) {
      v4f c = {0.f, 0.f, 0.f, 0.f};
      #pragma unroll
      for (int ks = 0; ks < 4; ks++)
        c = __builtin_amdgcn_mfma_f32_16x16x32_bf16(ap[ks], bv[dh2][ks], c, 0, 0, 0);
      c = __builtin_amdgcn_mfma_f32_16x16x32_bf16(at, bvt[dh2], c, 0, 0, 0);
      #pragma unroll
      for (int r = 0; r < 4; r++) {
        const int n = nt * 16 + quad * 4 + r;
        ao[((size_t)bw * NN + n) * CC + h * DH + dh2 * 16 + lr] = f2b(c[r]);
      }
    }
  }
}

// ---------------------------------------------------------------------------
// Proj v2: out = ao(bf16) @ w_proj + b_proj. 64 rows/block, NO LDS, NO
// barriers. Wave w owns output cols j in {3w..3w+2}; its 18 wpT fragments
// live in registers for the whole block. A-fragments read direct from
// global (LLC/L1-hot). out writes are NONTEMPORAL: out is never re-read,
// so skip L2/L3 allocation and keep the caches for qkv/ao.
// ---------------------------------------------------------------------------
__global__ __launch_bounds__(256) void proj_mfma(
    const unsigned short* __restrict__ ao,
    const unsigned short* __restrict__ wpT,
    const float* __restrict__ b_proj,
    float* __restrict__ out)
{
  const int tid  = threadIdx.x;
  const int wave = tid >> 6, lane = tid & 63;
  const int lr = lane & 15, lk8 = (lane >> 4) * 8, quad = lane >> 4;
  const size_t row0 = (size_t)blockIdx.x * 64;
  const int j0 = wave * 3;   // 3 j-strips of 16 cols per wave = 48 cols

  v8s bf[3][6];
  #pragma unroll
  for (int jj = 0; jj < 3; jj++)
    #pragma unroll
    for (int ks = 0; ks < 6; ks++)
      bf[jj][ks] = *(const v8s*)(wpT + (size_t)((j0 + jj) * 16 + lr) * CC + ks * 32 + lk8);

  float bvj[3];
  #pragma unroll
  for (int jj = 0; jj < 3; jj++) bvj[jj] = b_proj[(j0 + jj) * 16 + lr];

  #pragma unroll
  for (int rt = 0; rt < 4; rt++) {
    const size_t r0 = row0 + rt * 16;
    v8s a[6];
    #pragma unroll
    for (int ks = 0; ks < 6; ks++)
      a[ks] = *(const v8s*)(ao + (r0 + lr) * CC + ks * 32 + lk8);
    v4f acc[3];
    #pragma unroll
    for (int jj = 0; jj < 3; jj++) acc[jj] = (v4f){bvj[jj], bvj[jj], bvj[jj], bvj[jj]};
    #pragma unroll
    for (int ks = 0; ks < 6; ks++)
      #pragma unroll
      for (int jj = 0; jj < 3; jj++)
        acc[jj] = __builtin_amdgcn_mfma_f32_16x16x32_bf16(a[ks], bf[jj][ks], acc[jj], 0, 0, 0);
    #pragma unroll
    for (int jj = 0; jj < 3; jj++)
      #pragma unroll
      for (int r = 0; r < 4; r++)
        __builtin_nontemporal_store(acc[jj][r],
            &out[(r0 + quad * 4 + r) * CC + (j0 + jj) * 16 + lr]);
  }
}

// ---------------------------------------------------------------------------
// Launcher: runtime-sized chunking (single pass when ws fits full qkv —
// R22 proved chunk caps regress: 240-bw passes under-subscribe the grid).
// ---------------------------------------------------------------------------
extern "C" void kernel_launch(void* const* d_in, const int* in_sizes, int n_in,
                              void* d_out, int out_size, void* d_ws, size_t ws_size,
                              hipStream_t stream)
{
  const float* x          = (const float*)d_in[0];
  const float* mask       = (const float*)d_in[1];
  const float* w_qkv      = (const float*)d_in[2];
  const float* b_qkv      = (const float*)d_in[3];
  const float* w_proj     = (const float*)d_in[4];
  const float* b_proj     = (const float*)d_in[5];
  const float* bias_table = (const float*)d_in[6];
  const int*   pos        = (const int*)d_in[7];
  float* out = (float*)d_out;

  // ws layout (bf16 elems): biasNN | wqT | wpT | ao | qkvws (variable)
  unsigned short* biasNN = (unsigned short*)d_ws;                   // 1,244,160
  unsigned short* wqT    = biasNN + N_BIAS;                         //   110,592
  unsigned short* wpT    = wqT + N_WQT;                             //    36,864
  unsigned short* ao     = wpT + N_WPT;                             // 26,542,080
  unsigned short* qkvws  = ao + (size_t)B_ * NW * NN * CC;

  // runtime chunk sizing (single pass when ws allows)
  const size_t fixed_bytes = (size_t)(qkvws - (unsigned short*)d_ws) * sizeof(unsigned short);
  const size_t per_bw      = (size_t)HH * 3 * QKV_STRIDE * sizeof(unsigned short); // 165,888 B
  size_t avail = (ws_size > fixed_bytes) ? (ws_size - fixed_bytes) : 0;
  int maxchunk = (int)(avail / per_bw);
  if (maxchunk < 60)  maxchunk = 60;    // degenerate floor
  if (maxchunk > NBW) maxchunk = NBW;
  const int npass = (NBW + maxchunk - 1) / maxchunk;
  const int chunk = (NBW + npass - 1) / npass;

  const int prep_total = N_WQT + N_WPT + N_BIAS;
  prep_kernel<<<(prep_total + 255) / 256, 256, 0, stream>>>(
      w_qkv, w_proj, bias_table, pos, wqT, wpT, biasNN);

  for (int bw0 = 0; bw0 < NBW; bw0 += chunk) {
    const int cur = (NBW - bw0 < chunk) ? (NBW - bw0) : chunk;
    qkv_gemm<<<cur, 256, 0, stream>>>(x, b_qkv, wqT, qkvws, bw0);
    attn_bwh<<<cur * HH, 256, 0, stream>>>(qkvws, mask, biasNN, ao, bw0);
  }
  proj_mfma<<<(B_ * NW * NN) / 64, 256, 0, stream>>>(ao, wpT, b_proj, out);
}

// Round 25
// 411.053 us; speedup vs baseline: 1.1756x; 1.0360x over previous
//
#include <hip/hip_runtime.h>
#include <hip/hip_bf16.h>
#include <math.h>

// EarthAttention3D constants
#define B_   96
#define NW   10
#define NN   144
#define CC   192
#define HH   6
#define DH   32
#define SCALE 0.17677669529663687f  // 1/sqrt(32)

#define XP 200   // xs pitch (bf16): 400 B rows
#define PP 152   // Ps pitch: 304 B rows (12-bank row stride -> <=2-way, free)
#define NBW (B_ * NW)        // 960 (b,w) pairs total
#define QKV_STRIDE (NN * DH) // 4608 elems per (h,s) matrix

typedef __attribute__((ext_vector_type(8))) short v8s;            // 8 x bf16
typedef __attribute__((ext_vector_type(4))) unsigned short v4us;  // 4 x bf16
typedef __attribute__((ext_vector_type(4))) float v4f;            // MFMA acc

// fp32 -> bf16 RNE via the compiler's native lowering.
__device__ __forceinline__ unsigned short f2b(float f) {
  __hip_bfloat16 h = __float2bfloat16(f);
  return *reinterpret_cast<unsigned short*>(&h);
}
__device__ __forceinline__ float b2f(unsigned short s) {
  union { unsigned u; float f; } v; v.u = ((unsigned)s) << 16;
  return v.f;
}

#define N_WQT (576*192)
#define N_WPT (192*192)
#define N_BIAS (NW*HH*NN*NN)

// ---------------------------------------------------------------------------
// Prep: wqT = w_qkv^T bf16, wpT = w_proj^T bf16, biasNN gathered bf16.
// ---------------------------------------------------------------------------
__global__ __launch_bounds__(256) void prep_kernel(
    const float* __restrict__ w_qkv, const float* __restrict__ w_proj,
    const float* __restrict__ bias_table, const int* __restrict__ pos,
    unsigned short* __restrict__ wqT, unsigned short* __restrict__ wpT,
    unsigned short* __restrict__ biasNN)
{
  int i = blockIdx.x * 256 + threadIdx.x;
  if (i < N_WQT) {
    int n = i / 192, k = i % 192;
    wqT[i] = f2b(w_qkv[k * 576 + n]);
  } else if (i < N_WQT + N_WPT) {
    int j = i - N_WQT;
    int n = j / 192, k = j % 192;
    wpT[j] = f2b(w_proj[k * 192 + n]);
  } else if (i < N_WQT + N_WPT + N_BIAS) {
    int j = i - (N_WQT + N_WPT);
    int m = j % NN, n = (j / NN) % NN, h = (j / (NN * NN)) % HH, w = j / (NN * NN * HH);
    biasNN[j] = f2b(bias_table[(pos[n * NN + m] * NW + w) * HH + h]);
  }
}

// ---------------------------------------------------------------------------
// QKV GEMM v3: ONE block per bw (960 blocks), 256 thr / 4 waves, 57.6 KB LDS
// -> 2 blocks/CU. x staged ONCE (packed v4us stores), each wqT strip load
// feeds 54 MFMAs. wqT strip loads double-buffered in registers.
// ---------------------------------------------------------------------------
__global__ __launch_bounds__(256, 2) void qkv_gemm(
    const float* __restrict__ x, const float* __restrict__ b_qkv,
    const unsigned short* __restrict__ wqT,
    unsigned short* __restrict__ qkv, int bw0)
{
  __shared__ unsigned short xs[NN * XP];   // 57,600 B
  const int tid  = threadIdx.x;
  const int wave = tid >> 6, lane = tid & 63;
  const int lr = lane & 15, lk8 = (lane >> 4) * 8, quad = lane >> 4;
  const int bwl = blockIdx.x;
  const int bw  = bw0 + bwl;

  // stage all 144 rows of x as bf16 (packed 8B LDS stores)
  const float4* xp4 = (const float4*)(x + (size_t)bw * NN * CC);
  for (int i = tid; i < NN * (CC / 4); i += 256) {
    float4 f = xp4[i];
    int r = i / (CC / 4), c = (i % (CC / 4)) * 4;
    v4us pk;
    pk[0] = f2b(f.x); pk[1] = f2b(f.y); pk[2] = f2b(f.z); pk[3] = f2b(f.w);
    *(v4us*)&xs[r * XP + c] = pk;
  }
  __syncthreads();

  // software pipeline over the 9 col-strips this wave owns: c = wave + 4*i
  v8s bf0[6], bf1[6];
  {
    const unsigned short* w0 = wqT + (size_t)(wave * 16 + lr) * CC;
    #pragma unroll
    for (int ks = 0; ks < 6; ks++) bf0[ks] = *(const v8s*)&w0[ks * 32 + lk8];
  }

  #pragma unroll
  for (int i = 0; i < 9; i++) {
    const int c = wave + i * 4;
    // prefetch strip i+1 into the other buffer
    if (i + 1 < 9) {
      const unsigned short* wn = wqT + (size_t)((c + 4) * 16 + lr) * CC;
      if (i & 1) {
        #pragma unroll
        for (int ks = 0; ks < 6; ks++) bf0[ks] = *(const v8s*)&wn[ks * 32 + lk8];
      } else {
        #pragma unroll
        for (int ks = 0; ks < 6; ks++) bf1[ks] = *(const v8s*)&wn[ks * 32 + lk8];
      }
    }

    const int s = c / 12;
    const int h = (c % 12) >> 1;
    const int dhalf = c & 1;
    const float bv = b_qkv[c * 16 + lr];
    v4f acc[9];
    #pragma unroll
    for (int ii = 0; ii < 9; ii++) acc[ii] = (v4f){bv, bv, bv, bv};

    // 9 row-tiles x 6 ks: per ks read 9 independent A-frags, 9 indep MFMAs
    #pragma unroll
    for (int ks = 0; ks < 6; ks++) {
      v8s at[9];
      #pragma unroll
      for (int ii = 0; ii < 9; ii++)
        at[ii] = *(const v8s*)&xs[(ii * 16 + lr) * XP + ks * 32 + lk8];
      if (i & 1) {
        #pragma unroll
        for (int ii = 0; ii < 9; ii++)
          acc[ii] = __builtin_amdgcn_mfma_f32_16x16x32_bf16(at[ii], bf1[ks], acc[ii], 0, 0, 0);
      } else {
        #pragma unroll
        for (int ii = 0; ii < 9; ii++)
          acc[ii] = __builtin_amdgcn_mfma_f32_16x16x32_bf16(at[ii], bf0[ks], acc[ii], 0, 0, 0);
      }
    }

    if (s == 2) {
      // V: store transposed [d][n], 4 n packed per 8B store
      unsigned short* opT = qkv + ((size_t)(bwl * HH + h) * 3 + 2) * QKV_STRIDE
                          + (size_t)(dhalf * 16 + lr) * NN;
      #pragma unroll
      for (int ii = 0; ii < 9; ii++) {
        const int n0 = ii * 16 + quad * 4;
        v4us pk;
        #pragma unroll
        for (int r = 0; r < 4; r++) pk[r] = f2b(acc[ii][r]);
        *(v4us*)&opT[n0] = pk;
      }
    } else {
      unsigned short* op = qkv + ((size_t)(bwl * HH + h) * 3 + s) * QKV_STRIDE + dhalf * 16 + lr;
      #pragma unroll
      for (int ii = 0; ii < 9; ii++)
        #pragma unroll
        for (int r = 0; r < 4; r++) {
          const int n = ii * 16 + quad * 4 + r;
          op[n * DH] = f2b(acc[ii][r]);
        }
    }
  }
}

// ---------------------------------------------------------------------------
// Attention per (b,w,h): 256 thr / 4 waves, 43.8 KB LDS, (256,3).
// Phase B pure MFMA->LDS (barrier required: softmax rows span all waves'
// columns). Softmax row-ownership is ALIGNED with phase D's tile ownership
// (wave w -> tiles {w, w+4}, wave 0 also 8), and PV runs per-tile right
// after its rows are softmaxed by the SAME wave -> second barrier removed.
// Bit-identical arithmetic to the barriered version.
// ---------------------------------------------------------------------------
__global__ __launch_bounds__(256, 3) void attn_bwh(
    const unsigned short* __restrict__ qkv, const float* __restrict__ mask,
    const unsigned short* __restrict__ biasNN,
    unsigned short* __restrict__ ao, int bw0)
{
  __shared__ unsigned short Ps[NN * PP];   // 43,776 B

  const int tid  = threadIdx.x;
  const int wave = tid >> 6, lane = tid & 63;
  const int lr = lane & 15, lk8 = (lane >> 4) * 8, quad = lane >> 4;

  const int bwl = blockIdx.x / HH;
  const int h   = blockIdx.x % HH;
  const int bw  = bw0 + bwl;
  const int b   = bw / NW;
  const int w   = bw % NW;

  const unsigned short* qp = qkv + (size_t)(bwl * HH + h) * 3 * QKV_STRIDE;
  const unsigned short* kp = qp + QKV_STRIDE;
  const unsigned short* vT = qp + 2 * QKV_STRIDE;   // [32][144] transposed

  // hoist phase-D V^T fragments NOW: loads complete under the barrier drain
  v8s bv[2][4], bvt[2];
  #pragma unroll
  for (int dh2 = 0; dh2 < 2; dh2++) {
    const unsigned short* vrow = vT + (size_t)(dh2 * 16 + lr) * NN;
    #pragma unroll
    for (int ks = 0; ks < 4; ks++) bv[dh2][ks] = *(const v8s*)&vrow[ks * 32 + lk8];
    bvt[dh2] = *(const v8s*)&vrow[128 + (lk8 & 8)];
  }

  // ---- phase B: S = scale * q k^T -> bf16 in Ps (no global gathers) -------
  v8s aq[9];
  #pragma unroll
  for (int nt = 0; nt < 9; nt++)
    aq[nt] = *(const v8s*)&qp[(nt * 16 + lr) * DH + lk8];

  for (int mt = wave; mt < 9; mt += 4) {
    v8s bk = *(const v8s*)&kp[(mt * 16 + lr) * DH + lk8];
    const int m = mt * 16 + lr;
    #pragma unroll
    for (int nt = 0; nt < 9; nt++) {
      v4f c = {0.f, 0.f, 0.f, 0.f};
      c = __builtin_amdgcn_mfma_f32_16x16x32_bf16(aq[nt], bk, c, 0, 0, 0);
      #pragma unroll
      for (int r = 0; r < 4; r++) {
        const int n = nt * 16 + quad * 4 + r;
        Ps[n * PP + m] = f2b(c[r] * SCALE);
      }
    }
  }
  __syncthreads();   // rows need all waves' columns

  // ---- fused softmax + PV per owned tile (NO second barrier) --------------
  const unsigned short* bp = biasNN + (size_t)(w * HH + h) * NN * NN;
  const float* mp = mask + (size_t)b * NN * NN;
  const v8s vzero = {};

  for (int nt = wave; nt < 9; nt += 4) {
    // softmax the 16 rows of this tile: 4 iterations, one row per quad
    #pragma unroll
    for (int rq = 0; rq < 4; rq++) {
      const int row = nt * 16 + rq * 4 + quad;
      unsigned short* prow = &Ps[row * PP];
      const unsigned short* brow = bp + (size_t)row * NN;
      const float* mrow = mp + (size_t)row * NN;
      float bm[9];
      #pragma unroll
      for (int j = 0; j < 9; j++)
        bm[j] = b2f(brow[j * 16 + lr]) + mrow[j * 16 + lr];
      float e[9];
      float mx = -1e30f;
      #pragma unroll
      for (int j = 0; j < 9; j++) {
        e[j] = b2f(prow[j * 16 + lr]) + bm[j];
        mx = fmaxf(mx, e[j]);
      }
      #pragma unroll
      for (int off = 8; off; off >>= 1) mx = fmaxf(mx, __shfl_xor(mx, off, 64));
      float s = 0.f;
      #pragma unroll
      for (int j = 0; j < 9; j++) { e[j] = __expf(e[j] - mx); s += e[j]; }
      #pragma unroll
      for (int off = 8; off; off >>= 1) s += __shfl_xor(s, off, 64);
      const float inv = 1.f / s;
      #pragma unroll
      for (int j = 0; j < 9; j++) prow[j * 16 + lr] = f2b(e[j] * inv);
    }

    // PV for this tile: rows were written by THIS wave (LDS-hot, no barrier)
    v8s ap[4];
    #pragma unroll
    for (int ks = 0; ks < 4; ks++)
      ap[ks] = *(const v8s*)&Ps[(nt * 16 + lr) * PP + ks * 32 + lk8];
    v8s at = *(const v8s*)&Ps[(nt * 16 + lr) * PP + 128 + (lk8 & 8)];
    at = (quad < 2) ? at : vzero;   // k = 144..159 contributes zero
    #pragma unroll
    for (int dh2 = 0; dh2 < 2; dh2++) {
      v4f c = {0.f, 0.f, 0.f, 0.f};
      #pragma unroll
      for (int ks = 0; ks < 4; ks++)
        c = __builtin_amdgcn_mfma_f32_16x16x32_bf16(ap[ks], bv[dh2][ks], c, 0, 0, 0);
      c = __builtin_amdgcn_mfma_f32_16x16x32_bf16(at, bvt[dh2], c, 0, 0, 0);
      #pragma unroll
      for (int r = 0; r < 4; r++) {
        const int n = nt * 16 + quad * 4 + r;
        ao[((size_t)bw * NN + n) * CC + h * DH + dh2 * 16 + lr] = f2b(c[r]);
      }
    }
  }
}

// ---------------------------------------------------------------------------
// Proj v2: out = ao(bf16) @ w_proj + b_proj. 64 rows/block, NO LDS, NO
// barriers. Wave w owns output cols j in {3w..3w+2}; its 18 wpT fragments
// live in registers for the whole block. A-fragments read direct from
// global (LLC/L1-hot). out writes are NONTEMPORAL (never re-read).
// ---------------------------------------------------------------------------
__global__ __launch_bounds__(256) void proj_mfma(
    const unsigned short* __restrict__ ao,
    const unsigned short* __restrict__ wpT,
    const float* __restrict__ b_proj,
    float* __restrict__ out)
{
  const int tid  = threadIdx.x;
  const int wave = tid >> 6, lane = tid & 63;
  const int lr = lane & 15, lk8 = (lane >> 4) * 8, quad = lane >> 4;
  const size_t row0 = (size_t)blockIdx.x * 64;
  const int j0 = wave * 3;   // 3 j-strips of 16 cols per wave = 48 cols

  v8s bf[3][6];
  #pragma unroll
  for (int jj = 0; jj < 3; jj++)
    #pragma unroll
    for (int ks = 0; ks < 6; ks++)
      bf[jj][ks] = *(const v8s*)(wpT + (size_t)((j0 + jj) * 16 + lr) * CC + ks * 32 + lk8);

  float bvj[3];
  #pragma unroll
  for (int jj = 0; jj < 3; jj++) bvj[jj] = b_proj[(j0 + jj) * 16 + lr];

  #pragma unroll
  for (int rt = 0; rt < 4; rt++) {
    const size_t r0 = row0 + rt * 16;
    v8s a[6];
    #pragma unroll
    for (int ks = 0; ks < 6; ks++)
      a[ks] = *(const v8s*)(ao + (r0 + lr) * CC + ks * 32 + lk8);
    v4f acc[3];
    #pragma unroll
    for (int jj = 0; jj < 3; jj++) acc[jj] = (v4f){bvj[jj], bvj[jj], bvj[jj], bvj[jj]};
    #pragma unroll
    for (int ks = 0; ks < 6; ks++)
      #pragma unroll
      for (int jj = 0; jj < 3; jj++)
        acc[jj] = __builtin_amdgcn_mfma_f32_16x16x32_bf16(a[ks], bf[jj][ks], acc[jj], 0, 0, 0);
    #pragma unroll
    for (int jj = 0; jj < 3; jj++)
      #pragma unroll
      for (int r = 0; r < 4; r++)
        __builtin_nontemporal_store(acc[jj][r],
            &out[(r0 + quad * 4 + r) * CC + (j0 + jj) * 16 + lr]);
  }
}

// ---------------------------------------------------------------------------
// Launcher: runtime-sized chunking (single pass when ws fits full qkv —
// R22 proved chunk caps regress: 240-bw passes under-subscribe the grid).
// ---------------------------------------------------------------------------
extern "C" void kernel_launch(void* const* d_in, const int* in_sizes, int n_in,
                              void* d_out, int out_size, void* d_ws, size_t ws_size,
                              hipStream_t stream)
{
  const float* x          = (const float*)d_in[0];
  const float* mask       = (const float*)d_in[1];
  const float* w_qkv      = (const float*)d_in[2];
  const float* b_qkv      = (const float*)d_in[3];
  const float* w_proj     = (const float*)d_in[4];
  const float* b_proj     = (const float*)d_in[5];
  const float* bias_table = (const float*)d_in[6];
  const int*   pos        = (const int*)d_in[7];
  float* out = (float*)d_out;

  // ws layout (bf16 elems): biasNN | wqT | wpT | ao | qkvws (variable)
  unsigned short* biasNN = (unsigned short*)d_ws;                   // 1,244,160
  unsigned short* wqT    = biasNN + N_BIAS;                         //   110,592
  unsigned short* wpT    = wqT + N_WQT;                             //    36,864
  unsigned short* ao     = wpT + N_WPT;                             // 26,542,080
  unsigned short* qkvws  = ao + (size_t)B_ * NW * NN * CC;

  // runtime chunk sizing (single pass when ws allows)
  const size_t fixed_bytes = (size_t)(qkvws - (unsigned short*)d_ws) * sizeof(unsigned short);
  const size_t per_bw      = (size_t)HH * 3 * QKV_STRIDE * sizeof(unsigned short); // 165,888 B
  size_t avail = (ws_size > fixed_bytes) ? (ws_size - fixed_bytes) : 0;
  int maxchunk = (int)(avail / per_bw);
  if (maxchunk < 60)  maxchunk = 60;    // degenerate floor
  if (maxchunk > NBW) maxchunk = NBW;
  const int npass = (NBW + maxchunk - 1) / maxchunk;
  const int chunk = (NBW + npass - 1) / npass;

  const int prep_total = N_WQT + N_WPT + N_BIAS;
  prep_kernel<<<(prep_total + 255) / 256, 256, 0, stream>>>(
      w_qkv, w_proj, bias_table, pos, wqT, wpT, biasNN);

  for (int bw0 = 0; bw0 < NBW; bw0 += chunk) {
    const int cur = (NBW - bw0 < chunk) ? (NBW - bw0) : chunk;
    qkv_gemm<<<cur, 256, 0, stream>>>(x, b_qkv, wqT, qkvws, bw0);
    attn_bwh<<<cur * HH, 256, 0, stream>>>(qkvws, mask, biasNN, ao, bw0);
  }
  proj_mfma<<<(B_ * NW * NN) / 64, 256, 0, stream>>>(ao, wpT, b_proj, out);
}